// Round 1
// baseline (565.727 us; speedup 1.0000x reference)
//
#include <hip/hip_runtime.h>
#include <hip/hip_bf16.h>

#define DROP_PROB 0.5f
#define SCALE 2.0f   // 1/(1-p)

__global__ __launch_bounds__(256) void SparseDropout_kernel(
    const float4* __restrict__ in,
    const float4* __restrict__ noise,
    float4* __restrict__ out,
    int n4)
{
    int i = blockIdx.x * blockDim.x + threadIdx.x;
    if (i < n4) {
        float4 x = in[i];
        float4 nz = noise[i];
        float4 r;
        r.x = (nz.x >= DROP_PROB) ? x.x * SCALE : 0.0f;
        r.y = (nz.y >= DROP_PROB) ? x.y * SCALE : 0.0f;
        r.z = (nz.z >= DROP_PROB) ? x.z * SCALE : 0.0f;
        r.w = (nz.w >= DROP_PROB) ? x.w * SCALE : 0.0f;
        out[i] = r;
    }
}

extern "C" void kernel_launch(void* const* d_in, const int* in_sizes, int n_in,
                              void* d_out, int out_size, void* d_ws, size_t ws_size,
                              hipStream_t stream) {
    const float4* in    = (const float4*)d_in[0];
    const float4* noise = (const float4*)d_in[1];
    float4* out         = (float4*)d_out;

    int n  = out_size;          // 16384*4096 = 67108864, divisible by 4
    int n4 = n / 4;             // 16777216
    int block = 256;
    int grid = (n4 + block - 1) / block;   // 65536 blocks, no tail for this shape

    SparseDropout_kernel<<<grid, block, 0, stream>>>(in, noise, out, n4);
}